// Round 3
// baseline (741.512 us; speedup 1.0000x reference)
//
#include <hip/hip_runtime.h>
#include <math.h>

// ---------------------------------------------------------------------------
// GCN: h1 = relu(Agg(x) @ W1 + b1); h2 = relu(Agg(h1) @ W2 + b2);
//      g = mean-pool(h2, batch); out = relu(g@fc1+b)@fc2+b
// Agg(v)[n] = dinv[n] * ( sum_{e: dst=n} v'[src] + v'[n] ),  v' = v * dinv
// conv2 is SPLIT: k_agg2 (latency-bound gather, no LDS, max occupancy)
//              + k_mm2 (VALU-dense 64->128 GEMM, LDS-tiled).
// agg lives in-place in h2[n][0..63]; mm2 stages each tile to LDS before
// overwriting, so no extra workspace and no cross-block hazard.
// ---------------------------------------------------------------------------

#define SCB 1024  // scan elements per block
#define NB 16     // mm2 nodes per block-tile

__global__ void k_count_deg(const int* __restrict__ dst, int E, int* __restrict__ deg) {
  int i = blockIdx.x * blockDim.x + threadIdx.x;
  if (i < E) atomicAdd(&deg[dst[i]], 1);
}

// dinv + pre-scaled features x' = x * dinv
__global__ void k_prep(const int* __restrict__ deg, const float* __restrict__ x,
                       float* __restrict__ dinv, float* __restrict__ xp, int N) {
  int i = blockIdx.x * blockDim.x + threadIdx.x;
  if (i < N) {
    float di = 1.0f / sqrtf((float)(deg[i] + 1));  // +1 self loop; always > 0
    dinv[i] = di;
    float4 v = ((const float4*)x)[i];
    v.x *= di; v.y *= di; v.z *= di; v.w *= di;
    ((float4*)xp)[i] = v;
  }
}

// --- 3-phase exclusive scan of deg -> row_ptr[N+1], cursor seeded ---
__global__ void k_bsum(const int* __restrict__ deg, int* __restrict__ bsum, int N) {
  int b = blockIdx.x, t = threadIdx.x;
  int base = b * SCB;
  int s = 0;
  for (int i = t; i < SCB; i += 256) {
    int idx = base + i;
    if (idx < N) s += deg[idx];
  }
#pragma unroll
  for (int o = 32; o; o >>= 1) s += __shfl_xor(s, o);
  __shared__ int ws[4];
  if ((t & 63) == 0) ws[t >> 6] = s;
  __syncthreads();
  if (t == 0) bsum[b] = ws[0] + ws[1] + ws[2] + ws[3];
}

__global__ void k_scan_b(int* __restrict__ bsum, int nb) {  // 1 block; bsum[nb] <- total
  __shared__ int sh[1024];
  int t = threadIdx.x;
  int v = (t < nb) ? bsum[t] : 0;
  sh[t] = v;
  __syncthreads();
  for (int o = 1; o < 1024; o <<= 1) {
    int u = (t >= o) ? sh[t - o] : 0;
    __syncthreads();
    sh[t] += u;
    __syncthreads();
  }
  if (t < nb) bsum[t] = sh[t] - v;  // exclusive
  if (t == 1023) bsum[nb] = sh[1023];
}

__global__ void k_rowptr(const int* __restrict__ deg, const int* __restrict__ bsum,
                         int* __restrict__ row_ptr, int* __restrict__ cursor, int N) {
  int b = blockIdx.x, t = threadIdx.x;
  int base = b * SCB + t * 4;
  int d0 = 0, d1 = 0, d2 = 0, d3 = 0;
  if (base + 0 < N) d0 = deg[base + 0];
  if (base + 1 < N) d1 = deg[base + 1];
  if (base + 2 < N) d2 = deg[base + 2];
  if (base + 3 < N) d3 = deg[base + 3];
  int s = d0 + d1 + d2 + d3;
  __shared__ int sh[256];
  sh[t] = s;
  __syncthreads();
  for (int o = 1; o < 256; o <<= 1) {
    int u = (t >= o) ? sh[t - o] : 0;
    __syncthreads();
    sh[t] += u;
    __syncthreads();
  }
  int run = bsum[b] + sh[t] - s;
  if (base + 0 < N) { row_ptr[base + 0] = run; cursor[base + 0] = run; run += d0; }
  if (base + 1 < N) { row_ptr[base + 1] = run; cursor[base + 1] = run; run += d1; }
  if (base + 2 < N) { row_ptr[base + 2] = run; cursor[base + 2] = run; run += d2; }
  if (base + 3 < N) { row_ptr[base + 3] = run; cursor[base + 3] = run; run += d3; }
  if (b == 0 && t == 0) row_ptr[N] = bsum[gridDim.x];  // total
}

__global__ void k_fill(const int* __restrict__ src, const int* __restrict__ dst, int E,
                       int* __restrict__ cursor, int* __restrict__ csr_src) {
  int i = blockIdx.x * blockDim.x + threadIdx.x;
  if (i < E) {
    int d = dst[i];
    int pos = atomicAdd(&cursor[d], 1);
    csr_src[pos] = src[i];
  }
}

// conv1: 4 nodes per wave, 16-lane sub-group per node (mean deg ~16 -> good
// lane utilization). Reduce within sub-group, broadcast, 4x64 transform with
// lane = output channel. Writes h1' = relu(h1) * dinv[n].
__global__ void k_conv1(const float* __restrict__ xp, const int* __restrict__ row_ptr,
                        const int* __restrict__ csr_src, const float* __restrict__ dinv,
                        const float* __restrict__ W1, const float* __restrict__ b1,
                        float* __restrict__ h1p, int N) {
  int lane = threadIdx.x & 63;
  int sub = lane >> 4, sl = lane & 15;
  int wid = (blockIdx.x * blockDim.x + threadIdx.x) >> 6;
  int nw = (gridDim.x * blockDim.x) >> 6;
  const float4* x4 = (const float4*)xp;
  float w1 = W1[lane], w2 = W1[64 + lane], w3 = W1[128 + lane], w4 = W1[192 + lane];
  float bb = b1[lane];
  for (int base = wid * 4; base < N; base += nw * 4) {
    int n = base + sub;
    bool valid = (n < N);
    int e0 = 0, e1 = 0;
    if (valid) { e0 = row_ptr[n]; e1 = row_ptr[n + 1]; }
    float ax = 0.f, ay = 0.f, az = 0.f, aw = 0.f;
    for (int j = e0 + sl; j < e1; j += 16) {
      float4 xs = x4[csr_src[j]];
      ax += xs.x; ay += xs.y; az += xs.z; aw += xs.w;
    }
#pragma unroll
    for (int o = 8; o; o >>= 1) {
      ax += __shfl_xor(ax, o); ay += __shfl_xor(ay, o);
      az += __shfl_xor(az, o); aw += __shfl_xor(aw, o);
    }
    float di = 0.f;
    if (valid) {
      di = dinv[n];
      float4 xn = x4[n];
      ax += xn.x; ay += xn.y; az += xn.z; aw += xn.w;  // self loop
    }
#pragma unroll
    for (int g = 0; g < 4; ++g) {
      int nn = base + g;
      if (nn < N) {
        int srcl = g * 16;
        float bx = __shfl(ax, srcl), by = __shfl(ay, srcl);
        float bz = __shfl(az, srcl), bw = __shfl(aw, srcl);
        float dg = __shfl(di, srcl);
        float o0 = bb;
        o0 = fmaf(bx * dg, w1, o0);
        o0 = fmaf(by * dg, w2, o0);
        o0 = fmaf(bz * dg, w3, o0);
        o0 = fmaf(bw * dg, w4, o0);
        h1p[(size_t)nn * 64 + lane] = fmaxf(o0, 0.f) * dg;
      }
    }
  }
}

// agg2: pure gather. wave per node, lane = channel, 8 accumulators for MLP.
// Result (scaled by dinv[n]) stored into h2[n][0..63] (in-place, 128-stride).
__global__ void __launch_bounds__(256) k_agg2(
    const float* __restrict__ h1p, const int* __restrict__ row_ptr,
    const int* __restrict__ csr_src, const float* __restrict__ dinv,
    float* __restrict__ h2, int N) {
  int lane = threadIdx.x & 63;
  int wid = (blockIdx.x * blockDim.x + threadIdx.x) >> 6;
  int nw = (gridDim.x * blockDim.x) >> 6;
  for (int n = wid; n < N; n += nw) {
    int e0 = row_ptr[n], e1 = row_ptr[n + 1];
    float a0 = 0.f, a1 = 0.f, a2 = 0.f, a3 = 0.f;
    float a4 = 0.f, a5 = 0.f, a6 = 0.f, a7 = 0.f;
    int j = e0;
    for (; j + 8 <= e1; j += 8) {
      int s0 = csr_src[j + 0], s1 = csr_src[j + 1];
      int s2 = csr_src[j + 2], s3 = csr_src[j + 3];
      int s4 = csr_src[j + 4], s5 = csr_src[j + 5];
      int s6 = csr_src[j + 6], s7 = csr_src[j + 7];
      a0 += h1p[(size_t)s0 * 64 + lane]; a1 += h1p[(size_t)s1 * 64 + lane];
      a2 += h1p[(size_t)s2 * 64 + lane]; a3 += h1p[(size_t)s3 * 64 + lane];
      a4 += h1p[(size_t)s4 * 64 + lane]; a5 += h1p[(size_t)s5 * 64 + lane];
      a6 += h1p[(size_t)s6 * 64 + lane]; a7 += h1p[(size_t)s7 * 64 + lane];
    }
    for (; j + 2 <= e1; j += 2) {
      int s0 = csr_src[j], s1 = csr_src[j + 1];
      a0 += h1p[(size_t)s0 * 64 + lane]; a1 += h1p[(size_t)s1 * 64 + lane];
    }
    if (j < e1) a0 += h1p[(size_t)csr_src[j] * 64 + lane];
    float acc = ((a0 + a1) + (a2 + a3)) + ((a4 + a5) + (a6 + a7));
    acc += h1p[(size_t)n * 64 + lane];  // self loop (pre-scaled)
    h2[(size_t)n * 128 + lane] = acc * dinv[n];
  }
}

// mm2: dense [NB,64] @ [64,128] (+b2, relu) per block-tile, fp32 VALU.
// Reads agg from h2[n][0..63], stages transposed to LDS, overwrites h2[n][*].
__global__ void __launch_bounds__(256) k_mm2(
    const float* __restrict__ W2, const float* __restrict__ b2,
    float* __restrict__ h2, int N) {
  __shared__ float W2s[64 * 128];            // 32 KB
  __shared__ float aT[64][NB + 4];           // pad to 20 floats: 16B-aligned rows
  for (int i = threadIdx.x; i < 64 * 128; i += 256) W2s[i] = W2[i];
  int c = threadIdx.x & 127;    // output channel
  int half = threadIdx.x >> 7;  // node half (8 nodes each)
  int sr = threadIdx.x >> 6;    // stage row 0..3
  int sc = threadIdx.x & 63;    // stage col (input channel)
  float bias = b2[c];
  for (int base = blockIdx.x * NB; base < N; base += gridDim.x * NB) {
    __syncthreads();  // protect aT reuse (and cover W2s on first iter)
    for (int rr = sr; rr < NB; rr += 4) {
      int n = base + rr;
      aT[sc][rr] = (n < N) ? h2[(size_t)n * 128 + sc] : 0.f;
    }
    __syncthreads();
    float acc[8];
#pragma unroll
    for (int i = 0; i < 8; ++i) acc[i] = 0.f;
#pragma unroll
    for (int k = 0; k < 64; ++k) {
      float w = W2s[k * 128 + c];
      const float4* ap = (const float4*)&aT[k][half * 8];
      float4 v0 = ap[0], v1 = ap[1];
      acc[0] = fmaf(v0.x, w, acc[0]); acc[1] = fmaf(v0.y, w, acc[1]);
      acc[2] = fmaf(v0.z, w, acc[2]); acc[3] = fmaf(v0.w, w, acc[3]);
      acc[4] = fmaf(v1.x, w, acc[4]); acc[5] = fmaf(v1.y, w, acc[5]);
      acc[6] = fmaf(v1.z, w, acc[6]); acc[7] = fmaf(v1.w, w, acc[7]);
    }
#pragma unroll
    for (int i = 0; i < 8; ++i) {
      int n = base + half * 8 + i;
      if (n < N) h2[(size_t)n * 128 + c] = fmaxf(acc[i] + bias, 0.f);
    }
  }
}

__device__ __forceinline__ int lower_bound(const int* __restrict__ a, int n, int key) {
  int lo = 0, hi = n;
  while (lo < hi) {
    int m = (lo + hi) >> 1;
    if (a[m] < key) lo = m + 1; else hi = m;
  }
  return lo;
}

// block per graph: mean-pool h2 over [start,end), then fc1(relu)+fc2 on wave 0.
__global__ void k_pool_fc(const float* __restrict__ h2, const int* __restrict__ batch,
                          const float* __restrict__ fc1W, const float* __restrict__ fc1b,
                          const float* __restrict__ fc2W, const float* __restrict__ fc2b,
                          float* __restrict__ out, int N, int G) {
  int g = blockIdx.x;
  __shared__ int bounds[2];
  if (threadIdx.x == 0) bounds[0] = lower_bound(batch, N, g);
  if (threadIdx.x == 1) bounds[1] = lower_bound(batch, N, g + 1);
  __syncthreads();
  int beg = bounds[0], end = bounds[1];
  int c = threadIdx.x & 127;
  int gr = threadIdx.x >> 7;  // 2 node-stride groups
  float acc = 0.f;
  for (int i = beg + gr; i < end; i += 2) acc += h2[(size_t)i * 128 + c];
  __shared__ float red[256];
  __shared__ float grow[128];
  red[threadIdx.x] = acc;
  __syncthreads();
  if (threadIdx.x < 128) {
    float s = red[threadIdx.x] + red[threadIdx.x + 128];
    int cnt = end - beg;
    grow[threadIdx.x] = s / (float)max(cnt, 1);
  }
  __syncthreads();
  if (threadIdx.x < 64) {
    int c1 = threadIdx.x;
    float o = fc1b[c1];
#pragma unroll 8
    for (int k = 0; k < 128; ++k) o = fmaf(grow[k], fc1W[k * 64 + c1], o);
    o = fmaxf(o, 0.f);
    float v = o * fc2W[c1];
#pragma unroll
    for (int off = 32; off; off >>= 1) v += __shfl_xor(v, off);
    if (c1 == 0) out[g] = v + fc2b[0];
  }
}

extern "C" void kernel_launch(void* const* d_in, const int* in_sizes, int n_in,
                              void* d_out, int out_size, void* d_ws, size_t ws_size,
                              hipStream_t stream) {
  const float* x = (const float*)d_in[0];
  const int* ei = (const int*)d_in[1];
  const int* batch = (const int*)d_in[2];
  const float* W1 = (const float*)d_in[3];
  const float* b1 = (const float*)d_in[4];
  const float* W2 = (const float*)d_in[5];
  const float* b2 = (const float*)d_in[6];
  const float* fc1W = (const float*)d_in[7];
  const float* fc1b = (const float*)d_in[8];
  const float* fc2W = (const float*)d_in[9];
  const float* fc2b = (const float*)d_in[10];
  float* out = (float*)d_out;

  int N = in_sizes[0] / 4;   // 100000
  int E = in_sizes[1] / 2;   // 1600000
  int G = out_size;          // 1024
  const int* src = ei;
  const int* dst = ei + E;

  char* ws = (char*)d_ws;
  size_t off = 0;
  auto take = [&](size_t b) {
    char* p = ws + off;
    off += (b + 255) & ~(size_t)255;
    return p;
  };
  int nb = (N + SCB - 1) / SCB;  // 98
  int* deg      = (int*)take((size_t)N * 4);
  int* row_ptr  = (int*)take((size_t)(N + 1) * 4);
  int* cursor   = (int*)take((size_t)N * 4);
  int* bsum     = (int*)take((size_t)(nb + 1) * 4);
  float* dinv   = (float*)take((size_t)N * 4);
  float* xp     = (float*)take((size_t)N * 4 * 4);
  int* csr_src  = (int*)take((size_t)E * 4);
  float* h1p    = (float*)take((size_t)N * 64 * 4);
  float* h2     = (float*)take((size_t)N * 128 * 4);
  (void)ws_size;

  hipMemsetAsync(deg, 0, (size_t)N * 4, stream);
  k_count_deg<<<(E + 255) / 256, 256, 0, stream>>>(dst, E, deg);
  k_prep<<<(N + 255) / 256, 256, 0, stream>>>(deg, x, dinv, xp, N);
  k_bsum<<<nb, 256, 0, stream>>>(deg, bsum, N);
  k_scan_b<<<1, 1024, 0, stream>>>(bsum, nb);
  k_rowptr<<<nb, 256, 0, stream>>>(deg, bsum, row_ptr, cursor, N);
  k_fill<<<(E + 255) / 256, 256, 0, stream>>>(src, dst, E, cursor, csr_src);
  k_conv1<<<2048, 256, 0, stream>>>(xp, row_ptr, csr_src, dinv, W1, b1, h1p, N);
  k_agg2<<<4096, 256, 0, stream>>>(h1p, row_ptr, csr_src, dinv, h2, N);
  k_mm2<<<2048, 256, 0, stream>>>(W2, b2, h2, N);
  k_pool_fc<<<G, 256, 0, stream>>>(h2, batch, fc1W, fc1b, fc2W, fc2b, out, N, G);
}

// Round 4
// 402.480 us; speedup vs baseline: 1.8424x; 1.8424x over previous
//
#include <hip/hip_runtime.h>
#include <math.h>

// ---------------------------------------------------------------------------
// GCN: h1 = relu(Agg(x) @ W1 + b1); h2 = relu(Agg(h1) @ W2 + b2);
//      g = mean-pool(h2, batch); out = relu(g@fc1+b)@fc2+b
// Agg(v)[n] = dinv[n] * ( sum_{e: dst=n} v'[src] + v'[n] ),  v' = v * dinv
// Pipeline: CSR build -> conv1 -> agg2 (gather, dense [N][64]) ->
//           mm2pool (64->128 GEMM + relu + segmented mean-pool atomics) ->
//           fc (per-graph MLP head).  h2 is never materialized.
// ---------------------------------------------------------------------------

#define SCB 1024  // scan elements per block

__global__ void k_count_deg(const int* __restrict__ dst, int E, int* __restrict__ deg) {
  int i = blockIdx.x * blockDim.x + threadIdx.x;
  if (i < E) atomicAdd(&deg[dst[i]], 1);
}

// dinv + pre-scaled features x' = x * dinv
__global__ void k_prep(const int* __restrict__ deg, const float* __restrict__ x,
                       float* __restrict__ dinv, float* __restrict__ xp, int N) {
  int i = blockIdx.x * blockDim.x + threadIdx.x;
  if (i < N) {
    float di = 1.0f / sqrtf((float)(deg[i] + 1));  // +1 self loop; always > 0
    dinv[i] = di;
    float4 v = ((const float4*)x)[i];
    v.x *= di; v.y *= di; v.z *= di; v.w *= di;
    ((float4*)xp)[i] = v;
  }
}

// --- 3-phase exclusive scan of deg -> row_ptr[N+1], cursor seeded ---
__global__ void k_bsum(const int* __restrict__ deg, int* __restrict__ bsum, int N) {
  int b = blockIdx.x, t = threadIdx.x;
  int base = b * SCB;
  int s = 0;
  for (int i = t; i < SCB; i += 256) {
    int idx = base + i;
    if (idx < N) s += deg[idx];
  }
#pragma unroll
  for (int o = 32; o; o >>= 1) s += __shfl_xor(s, o);
  __shared__ int ws[4];
  if ((t & 63) == 0) ws[t >> 6] = s;
  __syncthreads();
  if (t == 0) bsum[b] = ws[0] + ws[1] + ws[2] + ws[3];
}

__global__ void k_scan_b(int* __restrict__ bsum, int nb) {  // 1 block; bsum[nb] <- total
  __shared__ int sh[1024];
  int t = threadIdx.x;
  int v = (t < nb) ? bsum[t] : 0;
  sh[t] = v;
  __syncthreads();
  for (int o = 1; o < 1024; o <<= 1) {
    int u = (t >= o) ? sh[t - o] : 0;
    __syncthreads();
    sh[t] += u;
    __syncthreads();
  }
  if (t < nb) bsum[t] = sh[t] - v;  // exclusive
  if (t == 1023) bsum[nb] = sh[1023];
}

__global__ void k_rowptr(const int* __restrict__ deg, const int* __restrict__ bsum,
                         int* __restrict__ row_ptr, int* __restrict__ cursor, int N) {
  int b = blockIdx.x, t = threadIdx.x;
  int base = b * SCB + t * 4;
  int d0 = 0, d1 = 0, d2 = 0, d3 = 0;
  if (base + 0 < N) d0 = deg[base + 0];
  if (base + 1 < N) d1 = deg[base + 1];
  if (base + 2 < N) d2 = deg[base + 2];
  if (base + 3 < N) d3 = deg[base + 3];
  int s = d0 + d1 + d2 + d3;
  __shared__ int sh[256];
  sh[t] = s;
  __syncthreads();
  for (int o = 1; o < 256; o <<= 1) {
    int u = (t >= o) ? sh[t - o] : 0;
    __syncthreads();
    sh[t] += u;
    __syncthreads();
  }
  int run = bsum[b] + sh[t] - s;
  if (base + 0 < N) { row_ptr[base + 0] = run; cursor[base + 0] = run; run += d0; }
  if (base + 1 < N) { row_ptr[base + 1] = run; cursor[base + 1] = run; run += d1; }
  if (base + 2 < N) { row_ptr[base + 2] = run; cursor[base + 2] = run; run += d2; }
  if (base + 3 < N) { row_ptr[base + 3] = run; cursor[base + 3] = run; run += d3; }
  if (b == 0 && t == 0) row_ptr[N] = bsum[gridDim.x];  // total
}

__global__ void k_fill(const int* __restrict__ src, const int* __restrict__ dst, int E,
                       int* __restrict__ cursor, int* __restrict__ csr_src) {
  int i = blockIdx.x * blockDim.x + threadIdx.x;
  if (i < E) {
    int d = dst[i];
    int pos = atomicAdd(&cursor[d], 1);
    csr_src[pos] = src[i];
  }
}

// conv1: 4 nodes per wave, 16-lane sub-group per node (mean deg ~16).
// Writes h1' = relu(h1) * dinv[n].
__global__ void k_conv1(const float* __restrict__ xp, const int* __restrict__ row_ptr,
                        const int* __restrict__ csr_src, const float* __restrict__ dinv,
                        const float* __restrict__ W1, const float* __restrict__ b1,
                        float* __restrict__ h1p, int N) {
  int lane = threadIdx.x & 63;
  int sub = lane >> 4, sl = lane & 15;
  int wid = (blockIdx.x * blockDim.x + threadIdx.x) >> 6;
  int nw = (gridDim.x * blockDim.x) >> 6;
  const float4* x4 = (const float4*)xp;
  float w1 = W1[lane], w2 = W1[64 + lane], w3 = W1[128 + lane], w4 = W1[192 + lane];
  float bb = b1[lane];
  for (int base = wid * 4; base < N; base += nw * 4) {
    int n = base + sub;
    bool valid = (n < N);
    int e0 = 0, e1 = 0;
    if (valid) { e0 = row_ptr[n]; e1 = row_ptr[n + 1]; }
    float ax = 0.f, ay = 0.f, az = 0.f, aw = 0.f;
    for (int j = e0 + sl; j < e1; j += 16) {
      float4 xs = x4[csr_src[j]];
      ax += xs.x; ay += xs.y; az += xs.z; aw += xs.w;
    }
#pragma unroll
    for (int o = 8; o; o >>= 1) {
      ax += __shfl_xor(ax, o); ay += __shfl_xor(ay, o);
      az += __shfl_xor(az, o); aw += __shfl_xor(aw, o);
    }
    float di = 0.f;
    if (valid) {
      di = dinv[n];
      float4 xn = x4[n];
      ax += xn.x; ay += xn.y; az += xn.z; aw += xn.w;  // self loop
    }
#pragma unroll
    for (int g = 0; g < 4; ++g) {
      int nn = base + g;
      if (nn < N) {
        int srcl = g * 16;
        float bx = __shfl(ax, srcl), by = __shfl(ay, srcl);
        float bz = __shfl(az, srcl), bw = __shfl(aw, srcl);
        float dg = __shfl(di, srcl);
        float o0 = bb;
        o0 = fmaf(bx * dg, w1, o0);
        o0 = fmaf(by * dg, w2, o0);
        o0 = fmaf(bz * dg, w3, o0);
        o0 = fmaf(bw * dg, w4, o0);
        h1p[(size_t)nn * 64 + lane] = fmaxf(o0, 0.f) * dg;
      }
    }
  }
}

// agg2: pure gather. wave per node, lane = channel, 8 accumulators for MLP.
// Writes dense agg[n][0..63] = dinv[n] * (sum + self).
__global__ void __launch_bounds__(256) k_agg2(
    const float* __restrict__ h1p, const int* __restrict__ row_ptr,
    const int* __restrict__ csr_src, const float* __restrict__ dinv,
    float* __restrict__ agg, int N) {
  int lane = threadIdx.x & 63;
  int wid = (blockIdx.x * blockDim.x + threadIdx.x) >> 6;
  int nw = (gridDim.x * blockDim.x) >> 6;
  for (int n = wid; n < N; n += nw) {
    int e0 = row_ptr[n], e1 = row_ptr[n + 1];
    float a0 = 0.f, a1 = 0.f, a2 = 0.f, a3 = 0.f;
    float a4 = 0.f, a5 = 0.f, a6 = 0.f, a7 = 0.f;
    int j = e0;
    for (; j + 8 <= e1; j += 8) {
      int s0 = csr_src[j + 0], s1 = csr_src[j + 1];
      int s2 = csr_src[j + 2], s3 = csr_src[j + 3];
      int s4 = csr_src[j + 4], s5 = csr_src[j + 5];
      int s6 = csr_src[j + 6], s7 = csr_src[j + 7];
      a0 += h1p[(size_t)s0 * 64 + lane]; a1 += h1p[(size_t)s1 * 64 + lane];
      a2 += h1p[(size_t)s2 * 64 + lane]; a3 += h1p[(size_t)s3 * 64 + lane];
      a4 += h1p[(size_t)s4 * 64 + lane]; a5 += h1p[(size_t)s5 * 64 + lane];
      a6 += h1p[(size_t)s6 * 64 + lane]; a7 += h1p[(size_t)s7 * 64 + lane];
    }
    for (; j + 2 <= e1; j += 2) {
      int s0 = csr_src[j], s1 = csr_src[j + 1];
      a0 += h1p[(size_t)s0 * 64 + lane]; a1 += h1p[(size_t)s1 * 64 + lane];
    }
    if (j < e1) a0 += h1p[(size_t)csr_src[j] * 64 + lane];
    float acc = ((a0 + a1) + (a2 + a3)) + ((a4 + a5) + (a6 + a7));
    acc += h1p[(size_t)n * 64 + lane];  // self loop (pre-scaled)
    agg[(size_t)n * 64 + lane] = acc * dinv[n];
  }
}

// mm2pool: per block, tile = 32 nodes. h2_tile = relu(agg_tile @ W2 + b2),
// immediately segment-reduced by graph id into gsum atomics (h2 never stored).
// Thread: c = tid&127 (out channel), g = tid>>7 -> nodes [g*16, g*16+16).
// aT = transposed agg tile in LDS (rows 144B -> 16B-aligned for b128 reads).
// W2 read from global per k (32KB, L2/L3-resident; no LDS copy).
__global__ void __launch_bounds__(256, 4) k_mm2pool(
    const float* __restrict__ agg, const int* __restrict__ batch,
    const float* __restrict__ W2, const float* __restrict__ b2,
    float* __restrict__ gsum, int N) {
  __shared__ float aT[64][36];  // [in_ch][node], pad 36 -> 144B rows
  __shared__ int gid_s[32];
  int tid = threadIdx.x;
  int base = blockIdx.x * 32;
  // stage: 32 nodes x 16 float4-chunks
  const float4* agg4 = (const float4*)agg;
  for (int idx = tid; idx < 32 * 16; idx += 256) {
    int node = idx >> 4, chunk = idx & 15;
    int n = base + node;
    float4 v = make_float4(0.f, 0.f, 0.f, 0.f);
    if (n < N) v = agg4[(size_t)n * 16 + chunk];
    aT[chunk * 4 + 0][node] = v.x;
    aT[chunk * 4 + 1][node] = v.y;
    aT[chunk * 4 + 2][node] = v.z;
    aT[chunk * 4 + 3][node] = v.w;
  }
  if (tid < 32) {
    int n = base + tid;
    gid_s[tid] = (n < N) ? batch[n] : -1;
  }
  __syncthreads();
  int c = tid & 127;
  int g = tid >> 7;
  float acc[16];
#pragma unroll
  for (int i = 0; i < 16; ++i) acc[i] = 0.f;
#pragma unroll 4
  for (int k = 0; k < 64; ++k) {
    float w = W2[k * 128 + c];
    const float4* ap = (const float4*)&aT[k][g * 16];
    float4 v0 = ap[0], v1 = ap[1], v2 = ap[2], v3 = ap[3];
    acc[0] = fmaf(v0.x, w, acc[0]);  acc[1] = fmaf(v0.y, w, acc[1]);
    acc[2] = fmaf(v0.z, w, acc[2]);  acc[3] = fmaf(v0.w, w, acc[3]);
    acc[4] = fmaf(v1.x, w, acc[4]);  acc[5] = fmaf(v1.y, w, acc[5]);
    acc[6] = fmaf(v1.z, w, acc[6]);  acc[7] = fmaf(v1.w, w, acc[7]);
    acc[8] = fmaf(v2.x, w, acc[8]);  acc[9] = fmaf(v2.y, w, acc[9]);
    acc[10] = fmaf(v2.z, w, acc[10]); acc[11] = fmaf(v2.w, w, acc[11]);
    acc[12] = fmaf(v3.x, w, acc[12]); acc[13] = fmaf(v3.y, w, acc[13]);
    acc[14] = fmaf(v3.z, w, acc[14]); acc[15] = fmaf(v3.w, w, acc[15]);
  }
  // segmented reduce over this thread's 16 sorted nodes -> gsum atomics
  float bias = b2[c];
  float run = 0.f;
  int cur = -1;
#pragma unroll
  for (int i = 0; i < 16; ++i) {
    int n = base + g * 16 + i;
    if (n < N) {
      int gg = gid_s[g * 16 + i];
      float v = fmaxf(acc[i] + bias, 0.f);
      if (gg == cur) {
        run += v;
      } else {
        if (cur >= 0) atomicAdd(&gsum[(size_t)cur * 128 + c], run);
        cur = gg;
        run = v;
      }
    }
  }
  if (cur >= 0) atomicAdd(&gsum[(size_t)cur * 128 + c], run);
}

__device__ __forceinline__ int lower_bound(const int* __restrict__ a, int n, int key) {
  int lo = 0, hi = n;
  while (lo < hi) {
    int m = (lo + hi) >> 1;
    if (a[m] < key) lo = m + 1; else hi = m;
  }
  return lo;
}

// fc head: block per graph. grow = gsum/cnt; out = relu(grow@fc1+b)@fc2+b.
__global__ void k_fc(const float* __restrict__ gsum, const int* __restrict__ batch,
                     const float* __restrict__ fc1W, const float* __restrict__ fc1b,
                     const float* __restrict__ fc2W, const float* __restrict__ fc2b,
                     float* __restrict__ out, int N, int G) {
  int g = blockIdx.x;
  int tid = threadIdx.x;
  __shared__ int bnd[2];
  if (tid == 0) bnd[0] = lower_bound(batch, N, g);
  if (tid == 1) bnd[1] = lower_bound(batch, N, g + 1);
  __shared__ float grow[128];
  __syncthreads();
  int cnt = bnd[1] - bnd[0];
  float inv = 1.0f / (float)max(cnt, 1);
  grow[tid] = gsum[(size_t)g * 128 + tid] * inv;
  __syncthreads();
  if (tid < 64) {
    float o = fc1b[tid];
#pragma unroll 8
    for (int k = 0; k < 128; ++k) o = fmaf(grow[k], fc1W[k * 64 + tid], o);
    o = fmaxf(o, 0.f);
    float v = o * fc2W[tid];
#pragma unroll
    for (int off = 32; off; off >>= 1) v += __shfl_xor(v, off);
    if (tid == 0) out[g] = v + fc2b[0];
  }
}

extern "C" void kernel_launch(void* const* d_in, const int* in_sizes, int n_in,
                              void* d_out, int out_size, void* d_ws, size_t ws_size,
                              hipStream_t stream) {
  const float* x = (const float*)d_in[0];
  const int* ei = (const int*)d_in[1];
  const int* batch = (const int*)d_in[2];
  const float* W1 = (const float*)d_in[3];
  const float* b1 = (const float*)d_in[4];
  const float* W2 = (const float*)d_in[5];
  const float* b2 = (const float*)d_in[6];
  const float* fc1W = (const float*)d_in[7];
  const float* fc1b = (const float*)d_in[8];
  const float* fc2W = (const float*)d_in[9];
  const float* fc2b = (const float*)d_in[10];
  float* out = (float*)d_out;

  int N = in_sizes[0] / 4;   // 100000
  int E = in_sizes[1] / 2;   // 1600000
  int G = out_size;          // 1024
  const int* src = ei;
  const int* dst = ei + E;

  char* ws = (char*)d_ws;
  size_t off = 0;
  auto take = [&](size_t b) {
    char* p = ws + off;
    off += (b + 255) & ~(size_t)255;
    return p;
  };
  int nb = (N + SCB - 1) / SCB;  // 98
  int* deg      = (int*)take((size_t)N * 4);
  int* row_ptr  = (int*)take((size_t)(N + 1) * 4);
  int* cursor   = (int*)take((size_t)N * 4);
  int* bsum     = (int*)take((size_t)(nb + 1) * 4);
  float* dinv   = (float*)take((size_t)N * 4);
  float* xp     = (float*)take((size_t)N * 4 * 4);
  int* csr_src  = (int*)take((size_t)E * 4);
  float* h1p    = (float*)take((size_t)N * 64 * 4);
  float* agg    = (float*)take((size_t)N * 64 * 4);
  float* gsum   = (float*)take((size_t)G * 128 * 4);
  (void)ws_size;

  hipMemsetAsync(deg, 0, (size_t)N * 4, stream);
  hipMemsetAsync(gsum, 0, (size_t)G * 128 * 4, stream);
  k_count_deg<<<(E + 255) / 256, 256, 0, stream>>>(dst, E, deg);
  k_prep<<<(N + 255) / 256, 256, 0, stream>>>(deg, x, dinv, xp, N);
  k_bsum<<<nb, 256, 0, stream>>>(deg, bsum, N);
  k_scan_b<<<1, 1024, 0, stream>>>(bsum, nb);
  k_rowptr<<<nb, 256, 0, stream>>>(deg, bsum, row_ptr, cursor, N);
  k_fill<<<(E + 255) / 256, 256, 0, stream>>>(src, dst, E, cursor, csr_src);
  k_conv1<<<2048, 256, 0, stream>>>(xp, row_ptr, csr_src, dinv, W1, b1, h1p, N);
  k_agg2<<<4096, 256, 0, stream>>>(h1p, row_ptr, csr_src, dinv, agg, N);
  k_mm2pool<<<(N + 31) / 32, 256, 0, stream>>>(agg, batch, W2, b2, gsum, N);
  k_fc<<<G, 128, 0, stream>>>(gsum, batch, fc1W, fc1b, fc2W, fc2b, out, N, G);
}

// Round 5
// 383.710 us; speedup vs baseline: 1.9325x; 1.0489x over previous
//
#include <hip/hip_runtime.h>
#include <math.h>

// ---------------------------------------------------------------------------
// GCN: h1 = relu(Agg(x) @ W1 + b1); h2 = relu(Agg(h1) @ W2 + b2);
//      g = mean-pool(h2, batch); out = relu(g@fc1+b)@fc2+b
// Agg(v)[n] = dinv[n] * ( sum_{e: dst=n} v'[src] + v'[n] ),  v' = v * dinv
// CSR build is a 2-stage bucket sort (bucket = dst>>8) so every scattered
// write lands in a small hot window -> no 64B-line write amplification.
// h2 is never materialized (mm2pool fuses GEMM+relu+mean-pool atomics).
// ---------------------------------------------------------------------------

#define SCB 1024   // scan elements per block (node scan)
#define EPB 2048   // edges per block in bucket passes
#define BSH 8      // nodes per bucket = 256
#define NBUK_MAX 512

// XCD-aware bijective block swizzle (8 XCDs): consecutive work ranges stay on
// one XCD's L2. Safe: pure permutation of block ids.
__device__ __forceinline__ int swz_block(int b, int nblk) {
  int xcd = b & 7, idx = b >> 3;
  int q = nblk >> 3, r = nblk & 7;
  return (xcd < r ? xcd * (q + 1) : r * (q + 1) + (xcd - r) * q) + idx;
}

// --- bucket histogram (LDS-aggregated) ---
__global__ void k_bukhist(const int* __restrict__ dst, int E,
                          int* __restrict__ bkcnt, int nbuk) {
  __shared__ int hist[NBUK_MAX];
  for (int i = threadIdx.x; i < nbuk; i += blockDim.x) hist[i] = 0;
  __syncthreads();
  int i0 = blockIdx.x * EPB, i1 = min(i0 + EPB, E);
  for (int i = i0 + threadIdx.x; i < i1; i += blockDim.x)
    atomicAdd(&hist[dst[i] >> BSH], 1);
  __syncthreads();
  for (int i = threadIdx.x; i < nbuk; i += blockDim.x)
    if (hist[i]) atomicAdd(&bkcnt[i], hist[i]);
}

// 1-block exclusive scan of bucket counts -> bcur (append cursors)
__global__ void k_scan_buk(const int* __restrict__ bkcnt, int* __restrict__ bcur,
                           int nbuk) {
  __shared__ int sh[NBUK_MAX];
  int t = threadIdx.x;
  int v = (t < nbuk) ? bkcnt[t] : 0;
  sh[t] = v;
  __syncthreads();
  for (int o = 1; o < NBUK_MAX; o <<= 1) {
    int u = (t >= o) ? sh[t - o] : 0;
    __syncthreads();
    sh[t] += u;
    __syncthreads();
  }
  if (t < nbuk) bcur[t] = sh[t] - v;  // exclusive
}

// bucket pass: block-aggregated append of (src,dst) into bucket-grouped ebuf.
__global__ void k_bucket(const int* __restrict__ src, const int* __restrict__ dst,
                         int E, int* __restrict__ bcur, int2* __restrict__ ebuf,
                         int nbuk) {
  __shared__ int hist[NBUK_MAX];
  __shared__ int hbase[NBUK_MAX];
  int t = threadIdx.x;
  int i0 = blockIdx.x * EPB, i1 = min(i0 + EPB, E);
  for (int i = t; i < nbuk; i += blockDim.x) hist[i] = 0;
  __syncthreads();
  for (int i = i0 + t; i < i1; i += blockDim.x)
    atomicAdd(&hist[dst[i] >> BSH], 1);
  __syncthreads();
  for (int i = t; i < nbuk; i += blockDim.x) {
    int c = hist[i];
    hbase[i] = c ? atomicAdd(&bcur[i], c) : 0;
  }
  __syncthreads();
  for (int i = t; i < nbuk; i += blockDim.x) hist[i] = 0;
  __syncthreads();
  for (int i = i0 + t; i < i1; i += blockDim.x) {
    int d = dst[i];
    int b = d >> BSH;
    int pos = hbase[b] + atomicAdd(&hist[b], 1);
    ebuf[pos] = make_int2(src[i], d);
  }
}

// degree count from bucket-grouped ebuf: atomics hit a hot ~1KB window.
__global__ void __launch_bounds__(256) k_deg2(const int2* __restrict__ ebuf, int E,
                                              int* __restrict__ deg) {
  int vb = swz_block(blockIdx.x, gridDim.x);
  int i = vb * 256 + threadIdx.x;
  if (i < E) atomicAdd(&deg[ebuf[i].y], 1);
}

// dinv + pre-scaled features x' = x * dinv
__global__ void k_prep(const int* __restrict__ deg, const float* __restrict__ x,
                       float* __restrict__ dinv, float* __restrict__ xp, int N) {
  int i = blockIdx.x * blockDim.x + threadIdx.x;
  if (i < N) {
    float di = 1.0f / sqrtf((float)(deg[i] + 1));  // +1 self loop; always > 0
    dinv[i] = di;
    float4 v = ((const float4*)x)[i];
    v.x *= di; v.y *= di; v.z *= di; v.w *= di;
    ((float4*)xp)[i] = v;
  }
}

// --- 3-phase exclusive scan of deg -> row_ptr[N+1], cursor seeded ---
__global__ void k_bsum(const int* __restrict__ deg, int* __restrict__ bsum, int N) {
  int b = blockIdx.x, t = threadIdx.x;
  int base = b * SCB;
  int s = 0;
  for (int i = t; i < SCB; i += 256) {
    int idx = base + i;
    if (idx < N) s += deg[idx];
  }
#pragma unroll
  for (int o = 32; o; o >>= 1) s += __shfl_xor(s, o);
  __shared__ int ws[4];
  if ((t & 63) == 0) ws[t >> 6] = s;
  __syncthreads();
  if (t == 0) bsum[b] = ws[0] + ws[1] + ws[2] + ws[3];
}

__global__ void k_scan_b(int* __restrict__ bsum, int nb) {  // 1 block; bsum[nb] <- total
  __shared__ int sh[1024];
  int t = threadIdx.x;
  int v = (t < nb) ? bsum[t] : 0;
  sh[t] = v;
  __syncthreads();
  for (int o = 1; o < 1024; o <<= 1) {
    int u = (t >= o) ? sh[t - o] : 0;
    __syncthreads();
    sh[t] += u;
    __syncthreads();
  }
  if (t < nb) bsum[t] = sh[t] - v;  // exclusive
  if (t == 1023) bsum[nb] = sh[1023];
}

__global__ void k_rowptr(const int* __restrict__ deg, const int* __restrict__ bsum,
                         int* __restrict__ row_ptr, int* __restrict__ cursor, int N) {
  int b = blockIdx.x, t = threadIdx.x;
  int base = b * SCB + t * 4;
  int d0 = 0, d1 = 0, d2 = 0, d3 = 0;
  if (base + 0 < N) d0 = deg[base + 0];
  if (base + 1 < N) d1 = deg[base + 1];
  if (base + 2 < N) d2 = deg[base + 2];
  if (base + 3 < N) d3 = deg[base + 3];
  int s = d0 + d1 + d2 + d3;
  __shared__ int sh[256];
  sh[t] = s;
  __syncthreads();
  for (int o = 1; o < 256; o <<= 1) {
    int u = (t >= o) ? sh[t - o] : 0;
    __syncthreads();
    sh[t] += u;
    __syncthreads();
  }
  int run = bsum[b] + sh[t] - s;
  if (base + 0 < N) { row_ptr[base + 0] = run; cursor[base + 0] = run; run += d0; }
  if (base + 1 < N) { row_ptr[base + 1] = run; cursor[base + 1] = run; run += d1; }
  if (base + 2 < N) { row_ptr[base + 2] = run; cursor[base + 2] = run; run += d2; }
  if (base + 3 < N) { row_ptr[base + 3] = run; cursor[base + 3] = run; run += d3; }
  if (b == 0 && t == 0) row_ptr[N] = bsum[gridDim.x];  // total
}

// exact-position fill from bucket-grouped ebuf: cursor atomics + csr writes
// both land in small per-bucket windows (cursor ~1KB, csr ~16KB) -> L2-hot.
__global__ void __launch_bounds__(256) k_fill2(const int2* __restrict__ ebuf, int E,
                                               int* __restrict__ cursor,
                                               int* __restrict__ csr_src) {
  int vb = swz_block(blockIdx.x, gridDim.x);
  int i = vb * 256 + threadIdx.x;
  if (i < E) {
    int2 e = ebuf[i];
    int pos = atomicAdd(&cursor[e.y], 1);
    csr_src[pos] = e.x;
  }
}

// conv1: 4 nodes per wave, 16-lane sub-group per node (mean deg ~16).
// Writes h1' = relu(h1) * dinv[n].
__global__ void k_conv1(const float* __restrict__ xp, const int* __restrict__ row_ptr,
                        const int* __restrict__ csr_src, const float* __restrict__ dinv,
                        const float* __restrict__ W1, const float* __restrict__ b1,
                        float* __restrict__ h1p, int N) {
  int lane = threadIdx.x & 63;
  int sub = lane >> 4, sl = lane & 15;
  int wid = (blockIdx.x * blockDim.x + threadIdx.x) >> 6;
  int nw = (gridDim.x * blockDim.x) >> 6;
  const float4* x4 = (const float4*)xp;
  float w1 = W1[lane], w2 = W1[64 + lane], w3 = W1[128 + lane], w4 = W1[192 + lane];
  float bb = b1[lane];
  for (int base = wid * 4; base < N; base += nw * 4) {
    int n = base + sub;
    bool valid = (n < N);
    int e0 = 0, e1 = 0;
    if (valid) { e0 = row_ptr[n]; e1 = row_ptr[n + 1]; }
    float ax = 0.f, ay = 0.f, az = 0.f, aw = 0.f;
    for (int j = e0 + sl; j < e1; j += 16) {
      float4 xs = x4[csr_src[j]];
      ax += xs.x; ay += xs.y; az += xs.z; aw += xs.w;
    }
#pragma unroll
    for (int o = 8; o; o >>= 1) {
      ax += __shfl_xor(ax, o); ay += __shfl_xor(ay, o);
      az += __shfl_xor(az, o); aw += __shfl_xor(aw, o);
    }
    float di = 0.f;
    if (valid) {
      di = dinv[n];
      float4 xn = x4[n];
      ax += xn.x; ay += xn.y; az += xn.z; aw += xn.w;  // self loop
    }
#pragma unroll
    for (int g = 0; g < 4; ++g) {
      int nn = base + g;
      if (nn < N) {
        int srcl = g * 16;
        float bx = __shfl(ax, srcl), by = __shfl(ay, srcl);
        float bz = __shfl(az, srcl), bw = __shfl(aw, srcl);
        float dg = __shfl(di, srcl);
        float o0 = bb;
        o0 = fmaf(bx * dg, w1, o0);
        o0 = fmaf(by * dg, w2, o0);
        o0 = fmaf(bz * dg, w3, o0);
        o0 = fmaf(bw * dg, w4, o0);
        h1p[(size_t)nn * 64 + lane] = fmaxf(o0, 0.f) * dg;
      }
    }
  }
}

// agg2: pure gather. wave per node, lane = channel, 8 accumulators for MLP.
// Writes dense agg[n][0..63] = dinv[n] * (sum + self).
__global__ void __launch_bounds__(256) k_agg2(
    const float* __restrict__ h1p, const int* __restrict__ row_ptr,
    const int* __restrict__ csr_src, const float* __restrict__ dinv,
    float* __restrict__ agg, int N) {
  int lane = threadIdx.x & 63;
  int wid = (blockIdx.x * blockDim.x + threadIdx.x) >> 6;
  int nw = (gridDim.x * blockDim.x) >> 6;
  for (int n = wid; n < N; n += nw) {
    int e0 = row_ptr[n], e1 = row_ptr[n + 1];
    float a0 = 0.f, a1 = 0.f, a2 = 0.f, a3 = 0.f;
    float a4 = 0.f, a5 = 0.f, a6 = 0.f, a7 = 0.f;
    int j = e0;
    for (; j + 8 <= e1; j += 8) {
      int s0 = csr_src[j + 0], s1 = csr_src[j + 1];
      int s2 = csr_src[j + 2], s3 = csr_src[j + 3];
      int s4 = csr_src[j + 4], s5 = csr_src[j + 5];
      int s6 = csr_src[j + 6], s7 = csr_src[j + 7];
      a0 += h1p[(size_t)s0 * 64 + lane]; a1 += h1p[(size_t)s1 * 64 + lane];
      a2 += h1p[(size_t)s2 * 64 + lane]; a3 += h1p[(size_t)s3 * 64 + lane];
      a4 += h1p[(size_t)s4 * 64 + lane]; a5 += h1p[(size_t)s5 * 64 + lane];
      a6 += h1p[(size_t)s6 * 64 + lane]; a7 += h1p[(size_t)s7 * 64 + lane];
    }
    for (; j + 2 <= e1; j += 2) {
      int s0 = csr_src[j], s1 = csr_src[j + 1];
      a0 += h1p[(size_t)s0 * 64 + lane]; a1 += h1p[(size_t)s1 * 64 + lane];
    }
    if (j < e1) a0 += h1p[(size_t)csr_src[j] * 64 + lane];
    float acc = ((a0 + a1) + (a2 + a3)) + ((a4 + a5) + (a6 + a7));
    acc += h1p[(size_t)n * 64 + lane];  // self loop (pre-scaled)
    agg[(size_t)n * 64 + lane] = acc * dinv[n];
  }
}

// mm2pool: per block, tile = 32 nodes. h2_tile = relu(agg_tile @ W2 + b2),
// immediately segment-reduced by graph id into gsum atomics (h2 never stored).
__global__ void __launch_bounds__(256, 4) k_mm2pool(
    const float* __restrict__ agg, const int* __restrict__ batch,
    const float* __restrict__ W2, const float* __restrict__ b2,
    float* __restrict__ gsum, int N) {
  __shared__ float aT[64][36];  // [in_ch][node], pad 36 -> 144B rows
  __shared__ int gid_s[32];
  int tid = threadIdx.x;
  int base = blockIdx.x * 32;
  const float4* agg4 = (const float4*)agg;
  for (int idx = tid; idx < 32 * 16; idx += 256) {
    int node = idx >> 4, chunk = idx & 15;
    int n = base + node;
    float4 v = make_float4(0.f, 0.f, 0.f, 0.f);
    if (n < N) v = agg4[(size_t)n * 16 + chunk];
    aT[chunk * 4 + 0][node] = v.x;
    aT[chunk * 4 + 1][node] = v.y;
    aT[chunk * 4 + 2][node] = v.z;
    aT[chunk * 4 + 3][node] = v.w;
  }
  if (tid < 32) {
    int n = base + tid;
    gid_s[tid] = (n < N) ? batch[n] : -1;
  }
  __syncthreads();
  int c = tid & 127;
  int g = tid >> 7;
  float acc[16];
#pragma unroll
  for (int i = 0; i < 16; ++i) acc[i] = 0.f;
#pragma unroll 4
  for (int k = 0; k < 64; ++k) {
    float w = W2[k * 128 + c];
    const float4* ap = (const float4*)&aT[k][g * 16];
    float4 v0 = ap[0], v1 = ap[1], v2 = ap[2], v3 = ap[3];
    acc[0] = fmaf(v0.x, w, acc[0]);  acc[1] = fmaf(v0.y, w, acc[1]);
    acc[2] = fmaf(v0.z, w, acc[2]);  acc[3] = fmaf(v0.w, w, acc[3]);
    acc[4] = fmaf(v1.x, w, acc[4]);  acc[5] = fmaf(v1.y, w, acc[5]);
    acc[6] = fmaf(v1.z, w, acc[6]);  acc[7] = fmaf(v1.w, w, acc[7]);
    acc[8] = fmaf(v2.x, w, acc[8]);  acc[9] = fmaf(v2.y, w, acc[9]);
    acc[10] = fmaf(v2.z, w, acc[10]); acc[11] = fmaf(v2.w, w, acc[11]);
    acc[12] = fmaf(v3.x, w, acc[12]); acc[13] = fmaf(v3.y, w, acc[13]);
    acc[14] = fmaf(v3.z, w, acc[14]); acc[15] = fmaf(v3.w, w, acc[15]);
  }
  float bias = b2[c];
  float run = 0.f;
  int cur = -1;
#pragma unroll
  for (int i = 0; i < 16; ++i) {
    int n = base + g * 16 + i;
    if (n < N) {
      int gg = gid_s[g * 16 + i];
      float v = fmaxf(acc[i] + bias, 0.f);
      if (gg == cur) {
        run += v;
      } else {
        if (cur >= 0) atomicAdd(&gsum[(size_t)cur * 128 + c], run);
        cur = gg;
        run = v;
      }
    }
  }
  if (cur >= 0) atomicAdd(&gsum[(size_t)cur * 128 + c], run);
}

__device__ __forceinline__ int lower_bound(const int* __restrict__ a, int n, int key) {
  int lo = 0, hi = n;
  while (lo < hi) {
    int m = (lo + hi) >> 1;
    if (a[m] < key) lo = m + 1; else hi = m;
  }
  return lo;
}

// fc head: block per graph. grow = gsum/cnt; out = relu(grow@fc1+b)@fc2+b.
__global__ void k_fc(const float* __restrict__ gsum, const int* __restrict__ batch,
                     const float* __restrict__ fc1W, const float* __restrict__ fc1b,
                     const float* __restrict__ fc2W, const float* __restrict__ fc2b,
                     float* __restrict__ out, int N, int G) {
  int g = blockIdx.x;
  int tid = threadIdx.x;
  __shared__ int bnd[2];
  if (tid == 0) bnd[0] = lower_bound(batch, N, g);
  if (tid == 1) bnd[1] = lower_bound(batch, N, g + 1);
  __shared__ float grow[128];
  __syncthreads();
  int cnt = bnd[1] - bnd[0];
  float inv = 1.0f / (float)max(cnt, 1);
  grow[tid] = gsum[(size_t)g * 128 + tid] * inv;
  __syncthreads();
  if (tid < 64) {
    float o = fc1b[tid];
#pragma unroll 8
    for (int k = 0; k < 128; ++k) o = fmaf(grow[k], fc1W[k * 64 + tid], o);
    o = fmaxf(o, 0.f);
    float v = o * fc2W[tid];
#pragma unroll
    for (int off = 32; off; off >>= 1) v += __shfl_xor(v, off);
    if (tid == 0) out[g] = v + fc2b[0];
  }
}

extern "C" void kernel_launch(void* const* d_in, const int* in_sizes, int n_in,
                              void* d_out, int out_size, void* d_ws, size_t ws_size,
                              hipStream_t stream) {
  const float* x = (const float*)d_in[0];
  const int* ei = (const int*)d_in[1];
  const int* batch = (const int*)d_in[2];
  const float* W1 = (const float*)d_in[3];
  const float* b1 = (const float*)d_in[4];
  const float* W2 = (const float*)d_in[5];
  const float* b2 = (const float*)d_in[6];
  const float* fc1W = (const float*)d_in[7];
  const float* fc1b = (const float*)d_in[8];
  const float* fc2W = (const float*)d_in[9];
  const float* fc2b = (const float*)d_in[10];
  float* out = (float*)d_out;

  int N = in_sizes[0] / 4;   // 100000
  int E = in_sizes[1] / 2;   // 1600000
  int G = out_size;          // 1024
  const int* src = ei;
  const int* dst = ei + E;

  char* ws = (char*)d_ws;
  size_t off = 0;
  auto take = [&](size_t b) {
    char* p = ws + off;
    off += (b + 255) & ~(size_t)255;
    return p;
  };
  int nb = (N + SCB - 1) / SCB;       // node-scan blocks (98)
  int nbuk = (N + 255) >> BSH;        // buckets (391), <= NBUK_MAX
  int ebl = (E + EPB - 1) / EPB;      // bucket-pass blocks (782)
  int epl = (E + 255) / 256;          // edge-parallel blocks (6250)
  int* deg      = (int*)take((size_t)N * 4);
  int* row_ptr  = (int*)take((size_t)(N + 1) * 4);
  int* cursor   = (int*)take((size_t)N * 4);
  int* bsum     = (int*)take((size_t)(nb + 1) * 4);
  int* bkcnt    = (int*)take((size_t)NBUK_MAX * 4);
  int* bcur     = (int*)take((size_t)NBUK_MAX * 4);
  float* dinv   = (float*)take((size_t)N * 4);
  float* xp     = (float*)take((size_t)N * 4 * 4);
  int2* ebuf    = (int2*)take((size_t)E * 8);
  int* csr_src  = (int*)take((size_t)E * 4);
  float* h1p    = (float*)take((size_t)N * 64 * 4);
  float* agg    = (float*)take((size_t)N * 64 * 4);
  float* gsum   = (float*)take((size_t)G * 128 * 4);
  (void)ws_size;

  hipMemsetAsync(deg, 0, (size_t)N * 4, stream);
  hipMemsetAsync(bkcnt, 0, (size_t)NBUK_MAX * 4, stream);
  hipMemsetAsync(gsum, 0, (size_t)G * 128 * 4, stream);

  // CSR build: bucket sort (dst>>8) -> localized deg count -> scan -> fill
  k_bukhist<<<ebl, 256, 0, stream>>>(dst, E, bkcnt, nbuk);
  k_scan_buk<<<1, NBUK_MAX, 0, stream>>>(bkcnt, bcur, nbuk);
  k_bucket<<<ebl, 256, 0, stream>>>(src, dst, E, bcur, ebuf, nbuk);
  k_deg2<<<epl, 256, 0, stream>>>(ebuf, E, deg);
  k_prep<<<(N + 255) / 256, 256, 0, stream>>>(deg, x, dinv, xp, N);
  k_bsum<<<nb, 256, 0, stream>>>(deg, bsum, N);
  k_scan_b<<<1, 1024, 0, stream>>>(bsum, nb);
  k_rowptr<<<nb, 256, 0, stream>>>(deg, bsum, row_ptr, cursor, N);
  k_fill2<<<epl, 256, 0, stream>>>(ebuf, E, cursor, csr_src);

  // GCN layers + head
  k_conv1<<<2048, 256, 0, stream>>>(xp, row_ptr, csr_src, dinv, W1, b1, h1p, N);
  k_agg2<<<4096, 256, 0, stream>>>(h1p, row_ptr, csr_src, dinv, agg, N);
  k_mm2pool<<<(N + 31) / 32, 256, 0, stream>>>(agg, batch, W2, b2, gsum, N);
  k_fc<<<G, 128, 0, stream>>>(gsum, batch, fc1W, fc1b, fc2W, fc2b, out, N, G);
}

// Round 6
// 271.201 us; speedup vs baseline: 2.7342x; 1.4149x over previous
//
#include <hip/hip_runtime.h>
#include <math.h>

// ---------------------------------------------------------------------------
// GCN: h1 = relu(Agg(x) @ W1 + b1); h2 = relu(Agg(h1) @ W2 + b2);
//      g = mean-pool(h2, batch); out = relu(g@fc1+b)@fc2+b
// Agg(v)[n] = dinv[n] * ( sum_{e: dst=n} v'[src] + v'[n] ),  v' = v * dinv
// CSR build: bucket sort by dst>>8 (packed 25-bit entries), then ONE BLOCK
// PER BUCKET finishes deg/row_ptr/fill entirely with LDS atomics -> zero
// per-edge global atomics, single-CU 16KB write windows (no amplification).
// h2 is never materialized (mm2pool fuses GEMM+relu+mean-pool atomics).
// ---------------------------------------------------------------------------

#define EPB 8192   // edges per block in bucket passes
#define BSH 8      // nodes per bucket = 256
#define NBUK_MAX 512

// --- bucket histogram (LDS-aggregated) ---
__global__ void k_bukhist(const int* __restrict__ dst, int E,
                          int* __restrict__ bkcnt, int nbuk) {
  __shared__ int hist[NBUK_MAX];
  for (int i = threadIdx.x; i < nbuk; i += blockDim.x) hist[i] = 0;
  __syncthreads();
  int i0 = blockIdx.x * EPB, i1 = min(i0 + EPB, E);
  for (int i = i0 + threadIdx.x; i < i1; i += blockDim.x)
    atomicAdd(&hist[dst[i] >> BSH], 1);
  __syncthreads();
  for (int i = threadIdx.x; i < nbuk; i += blockDim.x)
    if (hist[i]) atomicAdd(&bkcnt[i], hist[i]);
}

// 1-block exclusive scan of bucket counts -> bcur (append cursors)
__global__ void k_scan_buk(const int* __restrict__ bkcnt, int* __restrict__ bcur,
                           int nbuk) {
  __shared__ int sh[NBUK_MAX];
  int t = threadIdx.x;
  int v = (t < nbuk) ? bkcnt[t] : 0;
  sh[t] = v;
  __syncthreads();
  for (int o = 1; o < NBUK_MAX; o <<= 1) {
    int u = (t >= o) ? sh[t - o] : 0;
    __syncthreads();
    sh[t] += u;
    __syncthreads();
  }
  if (t < nbuk) bcur[t] = sh[t] - v;  // exclusive
}

// bucket pass: block-aggregated append of packed (src | (dst&255)<<17) into
// bucket-grouped ebuf. After this, bcur[b] == END of bucket b.
__global__ void k_bucket(const int* __restrict__ src, const int* __restrict__ dst,
                         int E, int* __restrict__ bcur, int* __restrict__ ebuf,
                         int nbuk) {
  __shared__ int hist[NBUK_MAX];
  __shared__ int hbase[NBUK_MAX];
  int t = threadIdx.x;
  int i0 = blockIdx.x * EPB, i1 = min(i0 + EPB, E);
  for (int i = t; i < nbuk; i += blockDim.x) hist[i] = 0;
  __syncthreads();
  for (int i = i0 + t; i < i1; i += blockDim.x)
    atomicAdd(&hist[dst[i] >> BSH], 1);
  __syncthreads();
  for (int i = t; i < nbuk; i += blockDim.x) {
    int c = hist[i];
    hbase[i] = c ? atomicAdd(&bcur[i], c) : 0;
  }
  __syncthreads();
  for (int i = t; i < nbuk; i += blockDim.x) hist[i] = 0;
  __syncthreads();
  for (int i = i0 + t; i < i1; i += blockDim.x) {
    int d = dst[i];
    int b = d >> BSH;
    int pos = hbase[b] + atomicAdd(&hist[b], 1);
    ebuf[pos] = src[i] | ((d & 255) << 17);  // src < 2^17
  }
}

// sortfill: one block per bucket. LDS hist -> LDS scan -> row_ptr write ->
// exact-position csr fill via LDS cursors. No global atomics anywhere.
__global__ void __launch_bounds__(256) k_sortfill(
    const int* __restrict__ ebuf, const int* __restrict__ bcur,
    int* __restrict__ row_ptr, int* __restrict__ csr_src, int N, int nbuk) {
  __shared__ int hist[256];
  __shared__ int sc[256];
  __shared__ int cur[256];
  int b = blockIdx.x, t = threadIdx.x;
  int e0 = (b == 0) ? 0 : bcur[b - 1];
  int e1 = bcur[b];
  hist[t] = 0;
  __syncthreads();
  for (int i = e0 + t; i < e1; i += 256)
    atomicAdd(&hist[ebuf[i] >> 17], 1);
  __syncthreads();
  int v = hist[t];
  sc[t] = v;
  __syncthreads();
  for (int o = 1; o < 256; o <<= 1) {
    int u = (t >= o) ? sc[t - o] : 0;
    __syncthreads();
    sc[t] += u;
    __syncthreads();
  }
  int excl = sc[t] - v;
  int node = (b << BSH) + t;
  if (node < N) row_ptr[node] = e0 + excl;
  if (b == nbuk - 1 && t == 0) row_ptr[N] = e1;  // == E
  cur[t] = excl;
  __syncthreads();
  for (int i = e0 + t; i < e1; i += 256) {
    int e = ebuf[i];
    int pos = e0 + atomicAdd(&cur[e >> 17], 1);
    csr_src[pos] = e & 0x1FFFF;
  }
}

// dinv (from row_ptr diffs) + pre-scaled features x' = x * dinv
__global__ void k_prep(const int* __restrict__ row_ptr, const float* __restrict__ x,
                       float* __restrict__ dinv, float* __restrict__ xp, int N) {
  int i = blockIdx.x * blockDim.x + threadIdx.x;
  if (i < N) {
    int deg = row_ptr[i + 1] - row_ptr[i];
    float di = 1.0f / sqrtf((float)(deg + 1));  // +1 self loop; always > 0
    dinv[i] = di;
    float4 v = ((const float4*)x)[i];
    v.x *= di; v.y *= di; v.z *= di; v.w *= di;
    ((float4*)xp)[i] = v;
  }
}

// conv1: 4 nodes per wave, 16-lane sub-group per node (mean deg ~16).
// Writes h1' = relu(h1) * dinv[n].
__global__ void k_conv1(const float* __restrict__ xp, const int* __restrict__ row_ptr,
                        const int* __restrict__ csr_src, const float* __restrict__ dinv,
                        const float* __restrict__ W1, const float* __restrict__ b1,
                        float* __restrict__ h1p, int N) {
  int lane = threadIdx.x & 63;
  int sub = lane >> 4, sl = lane & 15;
  int wid = (blockIdx.x * blockDim.x + threadIdx.x) >> 6;
  int nw = (gridDim.x * blockDim.x) >> 6;
  const float4* x4 = (const float4*)xp;
  float w1 = W1[lane], w2 = W1[64 + lane], w3 = W1[128 + lane], w4 = W1[192 + lane];
  float bb = b1[lane];
  for (int base = wid * 4; base < N; base += nw * 4) {
    int n = base + sub;
    bool valid = (n < N);
    int e0 = 0, e1 = 0;
    if (valid) { e0 = row_ptr[n]; e1 = row_ptr[n + 1]; }
    float ax = 0.f, ay = 0.f, az = 0.f, aw = 0.f;
    for (int j = e0 + sl; j < e1; j += 16) {
      float4 xs = x4[csr_src[j]];
      ax += xs.x; ay += xs.y; az += xs.z; aw += xs.w;
    }
#pragma unroll
    for (int o = 8; o; o >>= 1) {
      ax += __shfl_xor(ax, o); ay += __shfl_xor(ay, o);
      az += __shfl_xor(az, o); aw += __shfl_xor(aw, o);
    }
    float di = 0.f;
    if (valid) {
      di = dinv[n];
      float4 xn = x4[n];
      ax += xn.x; ay += xn.y; az += xn.z; aw += xn.w;  // self loop
    }
#pragma unroll
    for (int g = 0; g < 4; ++g) {
      int nn = base + g;
      if (nn < N) {
        int srcl = g * 16;
        float bx = __shfl(ax, srcl), by = __shfl(ay, srcl);
        float bz = __shfl(az, srcl), bw = __shfl(aw, srcl);
        float dg = __shfl(di, srcl);
        float o0 = bb;
        o0 = fmaf(bx * dg, w1, o0);
        o0 = fmaf(by * dg, w2, o0);
        o0 = fmaf(bz * dg, w3, o0);
        o0 = fmaf(bw * dg, w4, o0);
        h1p[(size_t)nn * 64 + lane] = fmaxf(o0, 0.f) * dg;
      }
    }
  }
}

// agg2: pure gather. wave per node, lane = channel, 8 accumulators for MLP.
// Writes dense agg[n][0..63] = dinv[n] * (sum + self).
__global__ void __launch_bounds__(256) k_agg2(
    const float* __restrict__ h1p, const int* __restrict__ row_ptr,
    const int* __restrict__ csr_src, const float* __restrict__ dinv,
    float* __restrict__ agg, int N) {
  int lane = threadIdx.x & 63;
  int wid = (blockIdx.x * blockDim.x + threadIdx.x) >> 6;
  int nw = (gridDim.x * blockDim.x) >> 6;
  for (int n = wid; n < N; n += nw) {
    int e0 = row_ptr[n], e1 = row_ptr[n + 1];
    float a0 = 0.f, a1 = 0.f, a2 = 0.f, a3 = 0.f;
    float a4 = 0.f, a5 = 0.f, a6 = 0.f, a7 = 0.f;
    int j = e0;
    for (; j + 8 <= e1; j += 8) {
      int s0 = csr_src[j + 0], s1 = csr_src[j + 1];
      int s2 = csr_src[j + 2], s3 = csr_src[j + 3];
      int s4 = csr_src[j + 4], s5 = csr_src[j + 5];
      int s6 = csr_src[j + 6], s7 = csr_src[j + 7];
      a0 += h1p[(size_t)s0 * 64 + lane]; a1 += h1p[(size_t)s1 * 64 + lane];
      a2 += h1p[(size_t)s2 * 64 + lane]; a3 += h1p[(size_t)s3 * 64 + lane];
      a4 += h1p[(size_t)s4 * 64 + lane]; a5 += h1p[(size_t)s5 * 64 + lane];
      a6 += h1p[(size_t)s6 * 64 + lane]; a7 += h1p[(size_t)s7 * 64 + lane];
    }
    for (; j + 2 <= e1; j += 2) {
      int s0 = csr_src[j], s1 = csr_src[j + 1];
      a0 += h1p[(size_t)s0 * 64 + lane]; a1 += h1p[(size_t)s1 * 64 + lane];
    }
    if (j < e1) a0 += h1p[(size_t)csr_src[j] * 64 + lane];
    float acc = ((a0 + a1) + (a2 + a3)) + ((a4 + a5) + (a6 + a7));
    acc += h1p[(size_t)n * 64 + lane];  // self loop (pre-scaled)
    agg[(size_t)n * 64 + lane] = acc * dinv[n];
  }
}

// mm2pool: per block, tile = 32 nodes. h2_tile = relu(agg_tile @ W2 + b2),
// immediately segment-reduced by graph id into gsum atomics (h2 never stored).
__global__ void __launch_bounds__(256, 4) k_mm2pool(
    const float* __restrict__ agg, const int* __restrict__ batch,
    const float* __restrict__ W2, const float* __restrict__ b2,
    float* __restrict__ gsum, int N) {
  __shared__ float aT[64][36];  // [in_ch][node], pad 36 -> 144B rows
  __shared__ int gid_s[32];
  int tid = threadIdx.x;
  int base = blockIdx.x * 32;
  const float4* agg4 = (const float4*)agg;
  for (int idx = tid; idx < 32 * 16; idx += 256) {
    int node = idx >> 4, chunk = idx & 15;
    int n = base + node;
    float4 v = make_float4(0.f, 0.f, 0.f, 0.f);
    if (n < N) v = agg4[(size_t)n * 16 + chunk];
    aT[chunk * 4 + 0][node] = v.x;
    aT[chunk * 4 + 1][node] = v.y;
    aT[chunk * 4 + 2][node] = v.z;
    aT[chunk * 4 + 3][node] = v.w;
  }
  if (tid < 32) {
    int n = base + tid;
    gid_s[tid] = (n < N) ? batch[n] : -1;
  }
  __syncthreads();
  int c = tid & 127;
  int g = tid >> 7;
  float acc[16];
#pragma unroll
  for (int i = 0; i < 16; ++i) acc[i] = 0.f;
#pragma unroll 4
  for (int k = 0; k < 64; ++k) {
    float w = W2[k * 128 + c];
    const float4* ap = (const float4*)&aT[k][g * 16];
    float4 v0 = ap[0], v1 = ap[1], v2 = ap[2], v3 = ap[3];
    acc[0] = fmaf(v0.x, w, acc[0]);  acc[1] = fmaf(v0.y, w, acc[1]);
    acc[2] = fmaf(v0.z, w, acc[2]);  acc[3] = fmaf(v0.w, w, acc[3]);
    acc[4] = fmaf(v1.x, w, acc[4]);  acc[5] = fmaf(v1.y, w, acc[5]);
    acc[6] = fmaf(v1.z, w, acc[6]);  acc[7] = fmaf(v1.w, w, acc[7]);
    acc[8] = fmaf(v2.x, w, acc[8]);  acc[9] = fmaf(v2.y, w, acc[9]);
    acc[10] = fmaf(v2.z, w, acc[10]); acc[11] = fmaf(v2.w, w, acc[11]);
    acc[12] = fmaf(v3.x, w, acc[12]); acc[13] = fmaf(v3.y, w, acc[13]);
    acc[14] = fmaf(v3.z, w, acc[14]); acc[15] = fmaf(v3.w, w, acc[15]);
  }
  float bias = b2[c];
  float run = 0.f;
  int cur = -1;
#pragma unroll
  for (int i = 0; i < 16; ++i) {
    int n = base + g * 16 + i;
    if (n < N) {
      int gg = gid_s[g * 16 + i];
      float v = fmaxf(acc[i] + bias, 0.f);
      if (gg == cur) {
        run += v;
      } else {
        if (cur >= 0) atomicAdd(&gsum[(size_t)cur * 128 + c], run);
        cur = gg;
        run = v;
      }
    }
  }
  if (cur >= 0) atomicAdd(&gsum[(size_t)cur * 128 + c], run);
}

__device__ __forceinline__ int lower_bound(const int* __restrict__ a, int n, int key) {
  int lo = 0, hi = n;
  while (lo < hi) {
    int m = (lo + hi) >> 1;
    if (a[m] < key) lo = m + 1; else hi = m;
  }
  return lo;
}

// fc head: block per graph. grow = gsum/cnt; out = relu(grow@fc1+b)@fc2+b.
__global__ void k_fc(const float* __restrict__ gsum, const int* __restrict__ batch,
                     const float* __restrict__ fc1W, const float* __restrict__ fc1b,
                     const float* __restrict__ fc2W, const float* __restrict__ fc2b,
                     float* __restrict__ out, int N, int G) {
  int g = blockIdx.x;
  int tid = threadIdx.x;
  __shared__ int bnd[2];
  if (tid == 0) bnd[0] = lower_bound(batch, N, g);
  if (tid == 1) bnd[1] = lower_bound(batch, N, g + 1);
  __shared__ float grow[128];
  __syncthreads();
  int cnt = bnd[1] - bnd[0];
  float inv = 1.0f / (float)max(cnt, 1);
  grow[tid] = gsum[(size_t)g * 128 + tid] * inv;
  __syncthreads();
  if (tid < 64) {
    float o = fc1b[tid];
#pragma unroll 8
    for (int k = 0; k < 128; ++k) o = fmaf(grow[k], fc1W[k * 64 + tid], o);
    o = fmaxf(o, 0.f);
    float v = o * fc2W[tid];
#pragma unroll
    for (int off = 32; off; off >>= 1) v += __shfl_xor(v, off);
    if (tid == 0) out[g] = v + fc2b[0];
  }
}

extern "C" void kernel_launch(void* const* d_in, const int* in_sizes, int n_in,
                              void* d_out, int out_size, void* d_ws, size_t ws_size,
                              hipStream_t stream) {
  const float* x = (const float*)d_in[0];
  const int* ei = (const int*)d_in[1];
  const int* batch = (const int*)d_in[2];
  const float* W1 = (const float*)d_in[3];
  const float* b1 = (const float*)d_in[4];
  const float* W2 = (const float*)d_in[5];
  const float* b2 = (const float*)d_in[6];
  const float* fc1W = (const float*)d_in[7];
  const float* fc1b = (const float*)d_in[8];
  const float* fc2W = (const float*)d_in[9];
  const float* fc2b = (const float*)d_in[10];
  float* out = (float*)d_out;

  int N = in_sizes[0] / 4;   // 100000
  int E = in_sizes[1] / 2;   // 1600000
  int G = out_size;          // 1024
  const int* src = ei;
  const int* dst = ei + E;

  char* ws = (char*)d_ws;
  size_t off = 0;
  auto take = [&](size_t b) {
    char* p = ws + off;
    off += (b + 255) & ~(size_t)255;
    return p;
  };
  int nbuk = (N + 255) >> BSH;        // buckets (391), <= NBUK_MAX
  int ebl = (E + EPB - 1) / EPB;      // bucket-pass blocks (196)
  int* row_ptr  = (int*)take((size_t)(N + 1) * 4);
  int* bkcnt    = (int*)take((size_t)NBUK_MAX * 4);
  int* bcur     = (int*)take((size_t)NBUK_MAX * 4);
  float* dinv   = (float*)take((size_t)N * 4);
  float* xp     = (float*)take((size_t)N * 4 * 4);
  int* ebuf     = (int*)take((size_t)E * 4);
  int* csr_src  = (int*)take((size_t)E * 4);
  float* h1p    = (float*)take((size_t)N * 64 * 4);
  float* agg    = (float*)take((size_t)N * 64 * 4);
  float* gsum   = (float*)take((size_t)G * 128 * 4);
  (void)ws_size;

  hipMemsetAsync(bkcnt, 0, (size_t)NBUK_MAX * 4, stream);
  hipMemsetAsync(gsum, 0, (size_t)G * 128 * 4, stream);

  // CSR build: bucket sort (dst>>8) -> per-bucket LDS sortfill
  k_bukhist<<<ebl, 256, 0, stream>>>(dst, E, bkcnt, nbuk);
  k_scan_buk<<<1, NBUK_MAX, 0, stream>>>(bkcnt, bcur, nbuk);
  k_bucket<<<ebl, 256, 0, stream>>>(src, dst, E, bcur, ebuf, nbuk);
  k_sortfill<<<nbuk, 256, 0, stream>>>(ebuf, bcur, row_ptr, csr_src, N, nbuk);

  // GCN layers + head
  k_prep<<<(N + 255) / 256, 256, 0, stream>>>(row_ptr, x, dinv, xp, N);
  k_conv1<<<2048, 256, 0, stream>>>(xp, row_ptr, csr_src, dinv, W1, b1, h1p, N);
  k_agg2<<<4096, 256, 0, stream>>>(h1p, row_ptr, csr_src, dinv, agg, N);
  k_mm2pool<<<(N + 31) / 32, 256, 0, stream>>>(agg, batch, W2, b2, gsum, N);
  k_fc<<<G, 128, 0, stream>>>(gsum, batch, fc1W, fc1b, fc2W, fc2b, out, N, G);
}